// Round 1
// baseline (208.747 us; speedup 1.0000x reference)
//
#include <hip/hip_runtime.h>

// Problem constants (match reference)
constexpr int kNEmo = 524288;
constexpr int kNAu  = 64;
constexpr int kN1   = 32;

// ws layout: [0,8) double accumulator; [256, 256+768) const arrays s[64],c[64],f[64]

__global__ __launch_bounds__(64) void setup_consts(
    const float* __restrict__ prob_all_au,
    const float* __restrict__ prob_AU_full,
    float* __restrict__ cst)
{
    int j = threadIdx.x;              // 0..63
    float p   = prob_all_au[j];
    float pA  = prob_AU_full[j];
    bool  occ = p > 0.6f;
    float inv = 1.0f / pA;
    float s, c, f;
    if (j < kN1) {
        if (occ) { s = p / pA;  c = 0.0f; f = 0.0f; }        // w = E * (p/pA), always > 0
        else     { s = -inv;    c = inv;  f = inv * 1e-5f; } // w = max(inv*(1-E), inv*1e-5)
    } else {
        // au2 = 1/pA regardless of occ (both branches of reference are 1/pA)
        if (occ) { s = inv;  c = 0.0f; }                     // w = E * inv
        else     { s = -inv; c = inv;  }                     // w = (1-E) * inv, unclamped
        f = 0.0f; // unused for j>=32
    }
    cst[j]       = s;
    cst[64 + j]  = c;
    cst[128 + j] = f;
}

__global__ __launch_bounds__(256) void row_prod(
    const float* __restrict__ cpt,   // [524288][64]
    const float* __restrict__ cst,
    float* __restrict__ out,         // per-row products
    double* __restrict__ acc)        // global denominator accumulator
{
    __shared__ float s_s[64], s_c[64], s_f[64];
    int tid = threadIdx.x;
    if (tid < 64) {
        s_s[tid] = cst[tid];
        s_c[tid] = cst[64 + tid];
        s_f[tid] = cst[128 + tid];
    }
    __syncthreads();

    int row = blockIdx.x * 256 + tid;
    const float4* rp = reinterpret_cast<const float4*>(cpt) + (size_t)row * 16;

    // 4 independent partial-product chains to break serial multiply dependency
    float pr0 = 1.0f, pr1 = 1.0f, pr2 = 1.0f, pr3 = 1.0f;

#pragma unroll
    for (int k = 0; k < 16; ++k) {
        float4 v = rp[k];
        const int j = 4 * k;

        float E0 = (v.x > 0.0f) ? v.x : 1e-5f;
        float E1 = (v.y > 0.0f) ? v.y : 1e-5f;
        float E2 = (v.z > 0.0f) ? v.z : 1e-5f;
        float E3 = (v.w > 0.0f) ? v.w : 1e-5f;

        float w0 = fmaf(s_s[j + 0], E0, s_c[j + 0]);
        float w1 = fmaf(s_s[j + 1], E1, s_c[j + 1]);
        float w2 = fmaf(s_s[j + 2], E2, s_c[j + 2]);
        float w3 = fmaf(s_s[j + 3], E3, s_c[j + 3]);

        if (j < kN1) {   // compile-time: only first half has the clamp
            w0 = fmaxf(w0, s_f[j + 0]);
            w1 = fmaxf(w1, s_f[j + 1]);
            w2 = fmaxf(w2, s_f[j + 2]);
            w3 = fmaxf(w3, s_f[j + 3]);
        }

        pr0 *= w0; pr1 *= w1; pr2 *= w2; pr3 *= w3;
    }

    float prod = (pr0 * pr1) * (pr2 * pr3);
    out[row] = prod;

    // block reduction of |prod| into the global denominator
    double val = fabs((double)prod);
#pragma unroll
    for (int off = 32; off > 0; off >>= 1)
        val += __shfl_down(val, off, 64);

    __shared__ double s_part[4];
    int wid = tid >> 6, lane = tid & 63;
    if (lane == 0) s_part[wid] = val;
    __syncthreads();
    if (tid == 0)
        atomicAdd(acc, s_part[0] + s_part[1] + s_part[2] + s_part[3]);
}

__global__ __launch_bounds__(256) void normalize(
    float* __restrict__ out, const double* __restrict__ acc)
{
    double s = *acc;
    if (!(s > 1e-12)) s = 1e-12;
    float invs = (float)(1.0 / s);

    int i = blockIdx.x * 256 + threadIdx.x;   // float4 index
    float4* o = reinterpret_cast<float4*>(out) + i;
    float4 v = *o;
    v.x *= invs; v.y *= invs; v.z *= invs; v.w *= invs;
    *o = v;
}

extern "C" void kernel_launch(void* const* d_in, const int* in_sizes, int n_in,
                              void* d_out, int out_size, void* d_ws, size_t ws_size,
                              hipStream_t stream)
{
    const float* prob_all_au  = (const float*)d_in[0]; // (64,1)
    const float* cpt          = (const float*)d_in[1]; // (524288,64)
    const float* prob_AU_full = (const float*)d_in[2]; // (64,1)
    float* out   = (float*)d_out;
    double* acc  = (double*)d_ws;
    float* cst   = (float*)((char*)d_ws + 256);

    hipMemsetAsync(d_ws, 0, 8, stream);  // zero the accumulator (ws is poisoned)

    setup_consts<<<1, 64, 0, stream>>>(prob_all_au, prob_AU_full, cst);
    row_prod<<<kNEmo / 256, 256, 0, stream>>>(cpt, cst, out, acc);
    normalize<<<kNEmo / 4 / 256, 256, 0, stream>>>(out, acc);
}

// Round 2
// 206.123 us; speedup vs baseline: 1.0127x; 1.0127x over previous
//
#include <hip/hip_runtime.h>
#include <float.h>

constexpr int kNEmo = 524288;

// One wave = 64 rows. Load i reads a contiguous 1KiB chunk:
//   float4 index (R*16 + i*64 + lane)  ->  row R + 4*i + (lane>>4), cols 4*(lane&15)..+3
// so each lane's columns are FIXED (j = 4*(lane&15)+q) and its 16 partials cover
// 16 different rows. A 4-stage halving butterfly over the low 4 lane bits yields
// one full row product per lane (row R + 4*(lane&15) + (lane>>4)).
__global__ __launch_bounds__(256) void row_prod(
    const float* __restrict__ cpt,           // [524288][64]
    const float* __restrict__ prob_all_au,   // [64]
    const float* __restrict__ prob_AU_full,  // [64]
    float* __restrict__ out,                 // [524288] row products
    double* __restrict__ acc)                // global |.| sum
{
    const int tid  = threadIdx.x;
    const int lane = tid & 63;
    const int wid  = tid >> 6;       // wave in block (0..3)
    const int q16  = lane & 15;      // column quarter

    // per-lane column constants: w = fmax(fma(s, E, c), f)
    float cs[4], cc[4], cf[4];
#pragma unroll
    for (int q = 0; q < 4; ++q) {
        int j = 4 * q16 + q;
        float p   = prob_all_au[j];
        float pA  = prob_AU_full[j];
        float inv = 1.0f / pA;
        bool  occ = p > 0.6f;
        if (j < 32) {
            if (occ) { cs[q] = p / pA; cc[q] = 0.0f; cf[q] = 0.0f; }          // w = E*(p/pA) > 0
            else     { cs[q] = -inv;   cc[q] = inv;  cf[q] = inv * 1e-5f; }   // w = max(inv*(1-E), inv*1e-5)
        } else {
            cs[q] = occ ?  inv : -inv;                                        // w = E*inv  or  (1-E)*inv
            cc[q] = occ ? 0.0f :  inv;
            cf[q] = -FLT_MAX;                                                 // no clamp for j>=32
        }
    }

    const int R = blockIdx.x * 256 + wid * 64;   // first row of this wave
    const float4* base = reinterpret_cast<const float4*>(cpt) + (size_t)R * 16 + lane;

    float part[16];
#pragma unroll
    for (int i = 0; i < 16; ++i) {
        float4 v = base[i * 64];                 // contiguous 1KiB per wave per i
        float E0 = (v.x > 0.0f) ? v.x : 1e-5f;
        float E1 = (v.y > 0.0f) ? v.y : 1e-5f;
        float E2 = (v.z > 0.0f) ? v.z : 1e-5f;
        float E3 = (v.w > 0.0f) ? v.w : 1e-5f;
        float w0 = fmaxf(fmaf(cs[0], E0, cc[0]), cf[0]);
        float w1 = fmaxf(fmaf(cs[1], E1, cc[1]), cf[1]);
        float w2 = fmaxf(fmaf(cs[2], E2, cc[2]), cf[2]);
        float w3 = fmaxf(fmaf(cs[3], E3, cc[3]), cf[3]);
        part[i] = (w0 * w1) * (w2 * w3);
    }

    // halving butterfly: 15 shuffles, all register indices compile-time.
    float s1[8];
#pragma unroll
    for (int i = 0; i < 8; ++i) {
        float mine = (lane & 1) ? part[2*i]   : part[2*i+1];
        float keep = (lane & 1) ? part[2*i+1] : part[2*i];
        s1[i] = keep * __shfl_xor(mine, 1, 64);
    }
    float s2[4];
#pragma unroll
    for (int i = 0; i < 4; ++i) {
        float mine = (lane & 2) ? s1[2*i]   : s1[2*i+1];
        float keep = (lane & 2) ? s1[2*i+1] : s1[2*i];
        s2[i] = keep * __shfl_xor(mine, 2, 64);
    }
    float s3[2];
#pragma unroll
    for (int i = 0; i < 2; ++i) {
        float mine = (lane & 4) ? s2[2*i]   : s2[2*i+1];
        float keep = (lane & 4) ? s2[2*i+1] : s2[2*i];
        s3[i] = keep * __shfl_xor(mine, 4, 64);
    }
    float mine4 = (lane & 8) ? s3[0] : s3[1];
    float keep4 = (lane & 8) ? s3[1] : s3[0];
    float s4 = keep4 * __shfl_xor(mine4, 8, 64);   // full product of row R + 4*(lane&15) + (lane>>4)

    out[R + 4 * (lane & 15) + (lane >> 4)] = s4;

    // |.|-sum: each lane holds a unique row's product
    double val = fabsf(s4);
#pragma unroll
    for (int off = 32; off > 0; off >>= 1)
        val += __shfl_down(val, off, 64);

    __shared__ double s_part[4];
    if (lane == 0) s_part[wid] = val;
    __syncthreads();
    if (tid == 0)
        atomicAdd(acc, s_part[0] + s_part[1] + s_part[2] + s_part[3]);
}

__global__ __launch_bounds__(256) void normalize(
    float* __restrict__ out, const double* __restrict__ acc)
{
    double s = *acc;
    if (!(s > 1e-12)) s = 1e-12;
    float invs = (float)(1.0 / s);

    int i = blockIdx.x * 256 + threadIdx.x;   // float4 index
    float4* o = reinterpret_cast<float4*>(out) + i;
    float4 v = *o;
    v.x *= invs; v.y *= invs; v.z *= invs; v.w *= invs;
    *o = v;
}

extern "C" void kernel_launch(void* const* d_in, const int* in_sizes, int n_in,
                              void* d_out, int out_size, void* d_ws, size_t ws_size,
                              hipStream_t stream)
{
    const float* prob_all_au  = (const float*)d_in[0]; // (64,1)
    const float* cpt          = (const float*)d_in[1]; // (524288,64)
    const float* prob_AU_full = (const float*)d_in[2]; // (64,1)
    float*  out = (float*)d_out;
    double* acc = (double*)d_ws;

    hipMemsetAsync(d_ws, 0, 8, stream);  // zero the denominator accumulator

    row_prod<<<kNEmo / 256, 256, 0, stream>>>(cpt, prob_all_au, prob_AU_full, out, acc);
    normalize<<<kNEmo / 4 / 256, 256, 0, stream>>>(out, acc);
}